// Round 10
// baseline (378.579 us; speedup 1.0000x reference)
//
#include <hip/hip_runtime.h>

#define TT   256
#define HID  30
#define LOG2E 1.4426950408889634f
#define HS   40        // h-row stride in bf16 (80B = 20 banks; rows n,n+8 alias -> 2-way, free)
#define XW   772       // x row stride (f32) in LDS

typedef __bf16 bf16x8_t __attribute__((ext_vector_type(8)));
typedef float  f32x4_t  __attribute__((ext_vector_type(4)));

__device__ __forceinline__ float fexp2(float x){
#if __has_builtin(__builtin_amdgcn_exp2f)
    return __builtin_amdgcn_exp2f(x);
#else
    return exp2f(x);
#endif
}
__device__ __forceinline__ float frcp(float x){
#if __has_builtin(__builtin_amdgcn_rcpf)
    return __builtin_amdgcn_rcpf(x);
#else
    return 1.f/x;
#endif
}
__device__ __forceinline__ float fsigmoid(float x){ return frcp(1.f + fexp2(-LOG2E*x)); }
__device__ __forceinline__ f32x4_t exp4(f32x4_t v){
    f32x4_t e; e[0]=fexp2(v[0]); e[1]=fexp2(v[1]); e[2]=fexp2(v[2]); e[3]=fexp2(v[3]); return e;
}
__device__ __forceinline__ f32x4_t rcp4(f32x4_t v){
    f32x4_t r; r[0]=frcp(v[0]); r[1]=frcp(v[1]); r[2]=frcp(v[2]); r[3]=frcp(v[3]); return r;
}
__device__ __forceinline__ f32x4_t sig4(f32x4_t v){ return rcp4(exp4(v*(-LOG2E)) + 1.f); }
__device__ __forceinline__ f32x4_t tanh4(f32x4_t v){ return rcp4(exp4(v*(-2.f*LOG2E)) + 1.f)*2.f - 1.f; }

#define MFMA(A,B,C) __builtin_amdgcn_mfma_f32_16x16x32_bf16(A,B,C,0,0,0)

// Async flag-synced 2-layer LSTM. Block = 4 waves, 16 rows, NO s_barrier in
// the recurrence loop. w0/w1 = layer0 unit-halves, w2/w3 = layer1 unit-halves.
// h0/h1 live in 4-slot LDS rings; per-wave progress counters (volatile LDS +
// acquire/release fences + s_sleep spin) gate readers. Waves drift up to ~3
// steps apart -> latency windows of one wave are filled by another on the
// same SIMD (2 blocks/CU -> 2 waves/SIMD from independent blocks as well).
// Gates lane-local (4 gate-tiles x 16 units per wave, no shfl); x LDS-resident.
__global__ __launch_bounds__(256)
void lstm_fused(const float* __restrict__ x,
    const float* __restrict__ Wih0, const float* __restrict__ Whh0,
    const float* __restrict__ bih0, const float* __restrict__ bhh0,
    const float* __restrict__ Wih1, const float* __restrict__ Whh1,
    const float* __restrict__ bih1, const float* __restrict__ bhh1,
    const float* __restrict__ Wfc1, const float* __restrict__ bfc1,
    const float* __restrict__ Wfc2, const float* __restrict__ bfc2,
    const float* __restrict__ Wfc3, const float* __restrict__ bfc3,
    float* __restrict__ out)
{
    __shared__ __align__(16) float  sx[16*XW];      // x slice; reused as FC scratch
    __shared__ __align__(16) __bf16 r0[4][16][HS];  // h0 ring: slot t&3 = h0(t) (+x01(t+1) at k30/31)
    __shared__ __align__(16) __bf16 r1[4][16][HS];  // h1 ring: slot t&3 = h1(t)
    __shared__ int prog[4];                          // stored value = completed_step + 1
    __shared__ float h1_last[16*32];

    const int tid  = threadIdx.x;
    const int lane = tid & 63;
    const int wvf  = tid >> 6;       // 0,1 = layer0 halves; 2,3 = layer1 halves
    const int grp  = wvf >> 1;       // 0 = L0, 1 = L1
    const int half = wvf & 1;        // unit half
    const int n    = lane & 15;
    const int q    = lane >> 4;
    const int u    = half*16 + n;    // hidden unit
    const bool ok  = (u < HID);
    const int uq   = ok ? u : 0;
    const int bbase = blockIdx.x * 16;

    // ---- stage x (16 rows x 768 f32) into LDS once ----
    {
        const float* xB = x + (size_t)bbase * 768;
        #pragma unroll
        for (int it = 0; it < 12; ++it) {
            int flat = (it*256 + tid) * 4;       // 0..12284
            int m = flat / 768;
            int o = flat - m*768;
            *(float4*)(&sx[m*XW + o]) = *(const float4*)(xB + (size_t)m*768 + o);
        }
    }

    // ---- resident B-fragments: 4 gate-tiles (G=i,f,g,o), 16 units per wave ----
    // L0: fbA = Whh0 (k30/31 = Wih0 cols 0,1); L1: fbA = Wih1, fbB = Whh1.
    bf16x8_t fbA[4], fbB[4];
    float bias[4], wx2[4];
    #pragma unroll
    for (int G = 0; G < 4; ++G) {
        const int row = G*HID + uq;
        #pragma unroll
        for (int j = 0; j < 8; ++j) {
            const int k = q*8 + j;
            float vA = 0.f, vB = 0.f;
            if (ok) {
                if (grp == 0) {
                    vA = (k < HID) ? Whh0[row*HID + k] : Wih0[row*3 + (k - HID)];
                } else if (k < HID) {
                    vA = Wih1[row*HID + k];
                    vB = Whh1[row*HID + k];
                }
            }
            fbA[G][j] = (__bf16)vA;
            fbB[G][j] = (__bf16)vB;
        }
        bias[G] = ok ? (grp == 0 ? bih0[row] + bhh0[row] : bih1[row] + bhh1[row]) : 0.f;
        wx2[G]  = (ok && grp == 0) ? Wih0[row*3 + 2] : 0.f;
    }

    // ---- init rings + flags; prologue x01(0) into r0[3] ----
    for (int i = tid; i < 4*16*HS; i += 256) {
        (&r0[0][0][0])[i] = (__bf16)0.f;
        (&r1[0][0][0])[i] = (__bf16)0.f;
    }
    if (tid < 4) prog[tid] = 0;
    __syncthreads();
    if (tid < 32)
        r0[3][tid>>1][30+(tid&1)] = (__bf16)sx[(tid>>1)*XW + (tid&1)];
    __syncthreads();

    volatile int* vp = prog;
    f32x4_t c = {0.f,0.f,0.f,0.f};

    #pragma unroll 1
    for (int t = 0; t < TT; ++t) {
        const int rs = (t+3) & 3, ws = t & 3;
        if (grp == 0) {
            // ---- layer 0, step t: needs h0(t-1) [p0>=t], slot-free [p1>=t-3] ----
            while (vp[0] < t || vp[1] < t || vp[2] < t-3 || vp[3] < t-3)
                __builtin_amdgcn_s_sleep(1);
            __builtin_amdgcn_fence(__ATOMIC_ACQUIRE, "workgroup");

            bf16x8_t A0 = *(const bf16x8_t*)(&r0[rs][n][q*8]);
            f32x4_t x2;
            #pragma unroll
            for (int r = 0; r < 4; ++r) x2[r] = sx[(q*4+r)*XW + t*3 + 2];
            f32x4_t d[4];
            #pragma unroll
            for (int G = 0; G < 4; ++G) d[G] = MFMA(A0, fbA[G], x2*wx2[G] + bias[G]);

            f32x4_t ii = sig4(d[0]), ff = sig4(d[1]);
            f32x4_t gg = tanh4(d[2]), oo = sig4(d[3]);
            c = ff*c + ii*gg;
            f32x4_t h = oo*tanh4(c);
            if (ok) {
                #pragma unroll
                for (int r = 0; r < 4; ++r) r0[ws][q*4+r][u] = (__bf16)h[r];
            }
            if (half == 0 && lane < 32) {          // x01(t+1) into slot ws
                int Tc = (t+1 < TT) ? t+1 : TT-1;
                r0[ws][lane>>1][30+(lane&1)] = (__bf16)sx[(lane>>1)*XW + Tc*3 + (lane&1)];
            }
            __builtin_amdgcn_fence(__ATOMIC_RELEASE, "workgroup");
            if (lane == 0) vp[wvf] = t + 1;
        } else {
            // ---- layer 1, step t: needs h0(t) [p0>=t+1], h1(t-1) [p1>=t] ----
            while (vp[0] < t+1 || vp[1] < t+1 || vp[2] < t || vp[3] < t)
                __builtin_amdgcn_s_sleep(1);
            __builtin_amdgcn_fence(__ATOMIC_ACQUIRE, "workgroup");

            bf16x8_t A1 = *(const bf16x8_t*)(&r0[ws][n][q*8]);   // h0(t)
            bf16x8_t A2 = *(const bf16x8_t*)(&r1[rs][n][q*8]);   // h1(t-1)
            f32x4_t d[4];
            #pragma unroll
            for (int G = 0; G < 4; ++G) {
                f32x4_t e = {bias[G], bias[G], bias[G], bias[G]};
                d[G] = MFMA(A1, fbA[G], e);
            }
            #pragma unroll
            for (int G = 0; G < 4; ++G) d[G] = MFMA(A2, fbB[G], d[G]);

            f32x4_t ii = sig4(d[0]), ff = sig4(d[1]);
            f32x4_t gg = tanh4(d[2]), oo = sig4(d[3]);
            c = ff*c + ii*gg;
            f32x4_t h = oo*tanh4(c);
            if (ok) {
                #pragma unroll
                for (int r = 0; r < 4; ++r) r1[ws][q*4+r][u] = (__bf16)h[r];
                if (t == TT-1) {
                    #pragma unroll
                    for (int r = 0; r < 4; ++r) h1_last[(q*4+r)*32 + u] = h[r];
                }
            }
            __builtin_amdgcn_fence(__ATOMIC_RELEASE, "workgroup");
            if (lane == 0) vp[wvf] = t + 1;
        }
    }
    __syncthreads();

    // ---- FC head (256 threads; scratch aliases sx) ----
    #pragma unroll
    for (int rep = 0; rep < 4; ++rep) {
        int idx = tid + rep*256;          // 16*64 outputs
        int m = idx >> 6, uu = idx & 63;
        float a = bfc1[uu];
        for (int k = 0; k < HID; ++k) a += h1_last[m*32+k] * Wfc1[uu*HID+k];
        sx[m*64+uu] = fmaxf(a, 0.f);
    }
    __syncthreads();
    #pragma unroll
    for (int rep = 0; rep < 2; ++rep) {
        int idx = tid + rep*256;          // 16*32 outputs
        int m = idx >> 5, v = idx & 31;
        float a = bfc2[v];
        for (int k = 0; k < 64; ++k) a += sx[m*64+k] * Wfc2[v*64+k];
        sx[1024 + m*32+v] = fmaxf(a, 0.f);
    }
    __syncthreads();
    if (tid < 16) {
        float a = bfc3[0];
        for (int k = 0; k < 32; ++k) a += sx[1024 + tid*32+k] * Wfc3[k];
        out[bbase + tid] = fsigmoid(a);
    }
}

extern "C" void kernel_launch(void* const* d_in, const int* in_sizes, int n_in,
                              void* d_out, int out_size, void* d_ws, size_t ws_size,
                              hipStream_t stream) {
    const float* x    = (const float*)d_in[0];
    const float* Wih0 = (const float*)d_in[1];
    const float* Whh0 = (const float*)d_in[2];
    const float* bih0 = (const float*)d_in[3];
    const float* bhh0 = (const float*)d_in[4];
    const float* Wih1 = (const float*)d_in[5];
    const float* Whh1 = (const float*)d_in[6];
    const float* bih1 = (const float*)d_in[7];
    const float* bhh1 = (const float*)d_in[8];
    const float* Wfc1 = (const float*)d_in[9];
    const float* bfc1 = (const float*)d_in[10];
    const float* Wfc2 = (const float*)d_in[11];
    const float* bfc2 = (const float*)d_in[12];
    const float* Wfc3 = (const float*)d_in[13];
    const float* bfc3 = (const float*)d_in[14];
    float* outp = (float*)d_out;

    hipLaunchKernelGGL(lstm_fused, dim3(512), dim3(256), 0, stream,
        x, Wih0, Whh0, bih0, bhh0, Wih1, Whh1, bih1, bhh1,
        Wfc1, bfc1, Wfc2, bfc2, Wfc3, bfc3, outp);
}